// Round 14
// baseline (115.003 us; speedup 1.0000x reference)
//
#include <hip/hip_runtime.h>
#include <hip/hip_bf16.h>

// B=256, x:[B,80,14,14] f32, w1:[512,80], b1:[512], w2:[512,512], b2:[512],
// w3:[512,4,14,14], fc_w:[80,2048], fc_b:[80] -> out:[B,80] f32.
// h2 = (w2@w1) x + (w2@b1+b2); bias folded as k-channel 80 (x col 80 = 1.0).
#define CIN 80
#define NSP 196
#define HWP 208        // hw padded 196->208 (13 n-tiles of 16)
#define KP  96         // k padded 80(+bias)->96 (3 MFMA k-steps of 32)
#define XST 104        // xs LDS row stride (ushorts)

#define NBA 1024       // Wc partials: 128 o-quads x 8 k-chunks of 64 (atomic-free)
#define NBC 512        // w3 -> bf16 transpose
#define NBD 64         // fc_w -> bf16 convert (same [l][k] layout)
#define NBE 16         // out init = fc_b (atomic target in kM)

typedef __attribute__((ext_vector_type(8))) short  short8;
typedef __attribute__((ext_vector_type(4))) float  floatx4;
typedef __attribute__((ext_vector_type(4))) unsigned short ushort4v;

static __device__ __forceinline__ unsigned short f2b(float f) {
    __hip_bfloat16 h = __float2bfloat16(f);
    return *(unsigned short*)&h;
}
static __device__ __forceinline__ float b2f(unsigned short u) {
    unsigned int x = ((unsigned int)u) << 16;
    float f; __builtin_memcpy(&f, &x, 4); return f;
}

// ---- kPre: Wc partials + w3 transpose + fc convert + out init ---------------
__global__ __launch_bounds__(384) void kPre(
    const float* __restrict__ w1, const float* __restrict__ b1,
    const float* __restrict__ w2, const float* __restrict__ w3,
    const float* __restrict__ fc_w, const float* __restrict__ fc_b,
    float* __restrict__ Wcf8, unsigned short* __restrict__ w3tb,
    unsigned short* __restrict__ fcl, float* __restrict__ out)
{
    const int blk = blockIdx.x, t = threadIdx.x;

    if (blk < NBA) {
        // Wcf8[kc][o][lc] = w2[o][m0:m0+64] @ (w1|b1)[m0:m0+64][lc]
        const int o4 = blk >> 3, kc = blk & 7, m0 = kc * 64;
        if (t < 324) {
            const int lc = t % 81, oi = t / 81;
            const int o = o4 * 4 + oi;
            const float* __restrict__ w2p = w2 + (size_t)o * 512 + m0;  // broadcast
            float part = 0.f;
            if (lc < CIN) {
                const float* __restrict__ w1p = w1 + (size_t)m0 * CIN + lc;
                #pragma unroll 8
                for (int i = 0; i < 64; ++i)
                    part = fmaf(w2p[i], w1p[(size_t)i * CIN], part);
            } else {
                #pragma unroll 8
                for (int i = 0; i < 64; ++i)
                    part = fmaf(w2p[i], b1[m0 + i], part);
            }
            Wcf8[((size_t)kc * 512 + o) * KP + lc] = part;   // only lc<=80 written
        }
    } else if (blk < NBA + NBC) {
        // w3 [g][4][196] -> w3tb [g][208][4] bf16, hw zero-padded
        const int g = blk - NBA;
        if (t < HWP) {
            ushort4v v;
            #pragma unroll
            for (int o = 0; o < 4; ++o)
                v[o] = f2b((t < NSP) ? w3[(size_t)g * 4 * NSP + o * NSP + t] : 0.f);
            *(ushort4v*)(w3tb + ((size_t)g * HWP + t) * 4) = v;
        }
    } else if (blk < NBA + NBC + NBD) {
        // fc_w [80][2048] f32 -> fcl [80][2048] bf16 (elementwise, coalesced)
        const int base = (blk - NBA - NBC) * 2560;   // 64 blocks * 2560 = 163840
        for (int i = t; i < 2560; i += 384) {
            const int idx = base + i;
            fcl[idx] = f2b(fc_w[idx]);
        }
    } else {
        // out init = fc_b broadcast (atomic target); 16 blocks * 1280 = 20480
        const int base = (blk - NBA - NBC - NBD) * 1280;
        for (int i = t; i < 1280; i += 384) {
            const int idx = base + i;
            out[idx] = fc_b[idx - (idx / CIN) * CIN];
        }
    }
}

// ---- kRed: Wcbf[512][96] bf16 = sum of 8 partials (+b2 on col 80, 0 pads) ---
__global__ __launch_bounds__(1024) void kRed(
    const float* __restrict__ Wcf8, const float* __restrict__ b2,
    unsigned short* __restrict__ Wcbf)
{
    const int idx = blockIdx.x * 1024 + threadIdx.x;   // 48 blocks = 512*96
    const int o = idx / KP, c = idx - o * KP;
    float s = 0.f;
    if (c <= CIN) {
        #pragma unroll
        for (int j = 0; j < 8; ++j)
            s += Wcf8[((size_t)j * 512 + o) * KP + c];
        if (c == CIN) s += b2[o];
    }
    Wcbf[idx] = f2b(s);
}

// ---- kM: block = (batch, 256-group half); 1024 thr = 16 waves x 16 groups. --
// 2 blocks/CU = 32 waves/CU (HW max) for latency hiding; fc partial + atomic.
__global__ __launch_bounds__(1024) void kM(
    const float* __restrict__ x, const unsigned short* __restrict__ Wcbf,
    const unsigned short* __restrict__ w3tb, const unsigned short* __restrict__ fcl,
    float* __restrict__ out)
{
    __shared__ __align__(16) unsigned short xs[HWP * XST];  // 43264 B
    __shared__ float gl[1024];                              // 4096 B
    const int b = blockIdx.x, h = blockIdx.y, t = threadIdx.x;

    // stage x[b]: [k][hw] f32 (float4: 49 quads/row, no row-crossing) -> xs[hw][k]
    {
        const floatx4* __restrict__ xb4 = (const floatx4*)(x + (size_t)b * CIN * NSP);
        for (int i4 = t; i4 < CIN * 49; i4 += 1024) {
            const int k = i4 / 49, hw4 = (i4 - k * 49) * 4;
            const floatx4 v = xb4[i4];
            xs[(hw4 + 0) * XST + k] = f2b(v[0]);
            xs[(hw4 + 1) * XST + k] = f2b(v[1]);
            xs[(hw4 + 2) * XST + k] = f2b(v[2]);
            xs[(hw4 + 3) * XST + k] = f2b(v[3]);
        }
        // k = 80 -> 1.0 (bias channel), 81..103 -> 0, for hw < 196
        for (int idx = t; idx < NSP * 24; idx += 1024) {
            const int hw = idx / 24, k = 80 + (idx - (idx / 24) * 24);
            xs[hw * XST + k] = (k == CIN) ? (unsigned short)0x3F80 : (unsigned short)0;
        }
        // hw pad rows 196..207: all-zero
        for (int idx = t; idx < 12 * XST; idx += 1024) {
            const int hw = NSP + idx / XST, k = idx - (idx / XST) * XST;
            xs[hw * XST + k] = 0;
        }
    }

    const int w = t >> 6, lane = t & 63;
    const int col = lane & 15, quad = lane >> 4;
    const int g = h * 256 + w * 16;        // wave's absolute group base (1 m-tile)

    // A-frag: 16 groups x 96 k, bf16 (12 VGPRs), from L2-hot Wcbf
    short8 A[3];
    {
        const unsigned short* __restrict__ ap =
            Wcbf + (size_t)(g + col) * KP + quad * 8;
        #pragma unroll
        for (int ks = 0; ks < 3; ++ks) A[ks] = *(const short8*)(ap + ks * 32);
    }

    float p[4][4];   // conv3 partials [r][o]
    #pragma unroll
    for (int r = 0; r < 4; ++r)
        #pragma unroll
        for (int o = 0; o < 4; ++o) p[r][o] = 0.f;

    const unsigned short* __restrict__ xrow = xs + col * XST + quad * 8;
    const unsigned short* __restrict__ wb =
        w3tb + ((size_t)(g + quad * 4) * HWP + col) * 4;

    __syncthreads();   // staging complete

    #pragma unroll 1
    for (int nt = 0; nt < 13; ++nt) {
        ushort4v wv[4];
        #pragma unroll
        for (int r = 0; r < 4; ++r)
            wv[r] = *(const ushort4v*)(wb + ((size_t)r * HWP + nt * 16) * 4);
        const unsigned short* __restrict__ xp = xrow + nt * 16 * XST;
        const short8 x0 = *(const short8*)(xp);
        const short8 x1 = *(const short8*)(xp + 32);
        const short8 x2 = *(const short8*)(xp + 64);
        floatx4 a0 = {0.f, 0.f, 0.f, 0.f};
        a0 = __builtin_amdgcn_mfma_f32_16x16x32_bf16(A[0], x0, a0, 0, 0, 0);
        a0 = __builtin_amdgcn_mfma_f32_16x16x32_bf16(A[1], x1, a0, 0, 0, 0);
        a0 = __builtin_amdgcn_mfma_f32_16x16x32_bf16(A[2], x2, a0, 0, 0, 0);
        // conv3 partials; C/D: col(hw)=lane&15, row(g)=quad*4+r  [m89-verified]
        #pragma unroll
        for (int r = 0; r < 4; ++r) {
            p[r][0] = fmaf(a0[r], b2f(wv[r][0]), p[r][0]);
            p[r][1] = fmaf(a0[r], b2f(wv[r][1]), p[r][1]);
            p[r][2] = fmaf(a0[r], b2f(wv[r][2]), p[r][2]);
            p[r][3] = fmaf(a0[r], b2f(wv[r][3]), p[r][3]);
        }
    }

    // reduce over 16 hw-lanes, relu -> gl[1024] (local to this 256-group half)
    #pragma unroll
    for (int r = 0; r < 4; ++r) {
        float q0 = p[r][0], q1 = p[r][1], q2 = p[r][2], q3 = p[r][3];
        #pragma unroll
        for (int s = 8; s >= 1; s >>= 1) {
            q0 += __shfl_down(q0, s, 16);
            q1 += __shfl_down(q1, s, 16);
            q2 += __shfl_down(q2, s, 16);
            q3 += __shfl_down(q3, s, 16);
        }
        if (col == 0) {
            const int glocal = w * 16 + quad * 4 + r;
            floatx4 ov = {fmaxf(q0, 0.f), fmaxf(q1, 0.f), fmaxf(q2, 0.f), fmaxf(q3, 0.f)};
            *(floatx4*)(gl + glocal * 4) = ov;
        }
    }
    __syncthreads();

    // fc partial over this block's 1024 k-cols: wave per l-row (16 w x 5 = 80).
    // Lane reads uint at fcl[l][h*1024 + j*128 + 2*lane] -> 256 B contig/instr.
    #pragma unroll 1
    for (int rr = 0; rr < 5; ++rr) {
        const int l = w * 5 + rr;
        const unsigned int* __restrict__ fr =
            (const unsigned int*)(fcl + (size_t)l * 2048 + h * 1024) + lane;
        const float* __restrict__ gp = gl + lane * 2;
        float s = 0.f;
        #pragma unroll
        for (int j = 0; j < 8; ++j) {
            const unsigned int u = fr[j * 64];
            float lo, hi;
            { unsigned int a = u << 16;          __builtin_memcpy(&lo, &a, 4); }
            { unsigned int a = u & 0xFFFF0000u;  __builtin_memcpy(&hi, &a, 4); }
            s = fmaf(gp[j * 128    ], lo, s);
            s = fmaf(gp[j * 128 + 1], hi, s);
        }
        #pragma unroll
        for (int sft = 32; sft >= 1; sft >>= 1) s += __shfl_down(s, sft, 64);
        if (lane == 0) atomicAdd(out + b * CIN + l, s);   // out pre-init = fc_b
    }
}

extern "C" void kernel_launch(void* const* d_in, const int* in_sizes, int n_in,
                              void* d_out, int out_size, void* d_ws, size_t ws_size,
                              hipStream_t stream) {
    const float* x    = (const float*)d_in[0];
    const float* w1   = (const float*)d_in[1];
    const float* b1   = (const float*)d_in[2];
    const float* w2   = (const float*)d_in[3];
    const float* b2   = (const float*)d_in[4];
    const float* w3   = (const float*)d_in[5];
    const float* fc_w = (const float*)d_in[6];
    const float* fc_b = (const float*)d_in[7];
    float* out = (float*)d_out;

    const int B = in_sizes[0] / (CIN * NSP);   // 256

    // workspace: Wcf8 | Wcbf | w3tb | fcl  (~2.9 MB)
    char* ws = (char*)d_ws;
    float* Wcf8 = (float*)ws;                                   // 8*512*96*4
    size_t off = (size_t)8 * 512 * KP * 4;
    unsigned short* Wcbf = (unsigned short*)(ws + off); off += 512 * KP * 2;
    unsigned short* w3tb = (unsigned short*)(ws + off); off += (size_t)512 * HWP * 4 * 2;
    unsigned short* fcl  = (unsigned short*)(ws + off);         // 80*2048*2

    kPre<<<NBA + NBC + NBD + NBE, 384, 0, stream>>>(
        w1, b1, w2, w3, fc_w, fc_b, Wcf8, w3tb, fcl, out);
    kRed<<<48, 1024, 0, stream>>>(Wcf8, b2, Wcbf);
    kM<<<dim3(B, 2), 1024, 0, stream>>>(x, Wcbf, w3tb, fcl, out);
}

// Round 15
// 112.064 us; speedup vs baseline: 1.0262x; 1.0262x over previous
//
#include <hip/hip_runtime.h>
#include <hip/hip_bf16.h>

// B=256, x:[B,80,14,14] f32, w1:[512,80], b1:[512], w2:[512,512], b2:[512],
// w3:[512,4,14,14], fc_w:[80,2048], fc_b:[80] -> out:[B,80] f32.
// h2 = (w2@w1) x + (w2@b1+b2); bias folded as k-channel 80 (x col 80 = 1.0).
#define CIN 80
#define NSP 196
#define HWP 208        // hw padded 196->208 (13 n-tiles of 16)
#define KP  96         // k padded 80(+bias)->96 (3 MFMA k-steps of 32)
#define XST 104        // xs LDS row stride (ushorts)

#define NBA 1024       // Wc partials: 128 o-quads x 8 k-chunks of 64 (atomic-free)
#define NBC 128        // w3 -> packed bf16 w3q[gq][hw][16]
#define NBD 64         // fc_w -> bf16 convert (same [l][k] layout)

typedef __attribute__((ext_vector_type(8))) short  short8;
typedef __attribute__((ext_vector_type(4))) float  floatx4;
typedef __attribute__((ext_vector_type(4))) unsigned short ushort4v;
typedef __attribute__((ext_vector_type(8))) unsigned short ushort8v;

static __device__ __forceinline__ unsigned short f2b(float f) {
    __hip_bfloat16 h = __float2bfloat16(f);
    return *(unsigned short*)&h;
}
static __device__ __forceinline__ float b2f(unsigned short u) {
    unsigned int x = ((unsigned int)u) << 16;
    float f; __builtin_memcpy(&f, &x, 4); return f;
}

// ---- kPre: Wc k-split partials + w3 pack + fc convert -----------------------
__global__ __launch_bounds__(384) void kPre(
    const float* __restrict__ w1, const float* __restrict__ b1,
    const float* __restrict__ w2, const float* __restrict__ w3,
    const float* __restrict__ fc_w,
    float* __restrict__ Wcf8, unsigned short* __restrict__ w3q,
    unsigned short* __restrict__ fcl)
{
    const int blk = blockIdx.x, t = threadIdx.x;

    if (blk < NBA) {
        // Wcf8[kc][o][lc] = w2[o][m0:m0+64] @ (w1|b1)[m0:m0+64][lc]
        const int o4 = blk >> 3, kc = blk & 7, m0 = kc * 64;
        if (t < 324) {
            const int lc = t % 81, oi = t / 81;
            const int o = o4 * 4 + oi;
            const float* __restrict__ w2p = w2 + (size_t)o * 512 + m0;  // broadcast
            float part = 0.f;
            if (lc < CIN) {
                const float* __restrict__ w1p = w1 + (size_t)m0 * CIN + lc;
                #pragma unroll 8
                for (int i = 0; i < 64; ++i)
                    part = fmaf(w2p[i], w1p[(size_t)i * CIN], part);
            } else {
                #pragma unroll 8
                for (int i = 0; i < 64; ++i)
                    part = fmaf(w2p[i], b1[m0 + i], part);
            }
            Wcf8[((size_t)kc * 512 + o) * KP + lc] = part;   // only lc<=80 written
        }
    } else if (blk < NBA + NBC) {
        // w3 [g][4][196] -> w3q [gq][208][16] bf16: entry r*4+o = w3[gq*4+r][o][hw]
        const int gq = blk - NBA;
        if (t < HWP) {
            ushort8v v0, v1;
            #pragma unroll
            for (int r = 0; r < 4; ++r)
                #pragma unroll
                for (int o = 0; o < 4; ++o) {
                    const unsigned short e = f2b(
                        (t < NSP) ? w3[(size_t)((gq * 4 + r) * 4 + o) * NSP + t] : 0.f);
                    if (r < 2) v0[r * 4 + o] = e; else v1[(r - 2) * 4 + o] = e;
                }
            unsigned short* dst = w3q + ((size_t)gq * HWP + t) * 16;
            *(ushort8v*)(dst) = v0;
            *(ushort8v*)(dst + 8) = v1;
        }
    } else {
        // fc_w [80][2048] f32 -> fcl [80][2048] bf16 (elementwise, coalesced)
        const int base = (blk - NBA - NBC) * 2560;   // 64 blocks * 2560 = 163840
        for (int i = t; i < 2560; i += 384) {
            const int idx = base + i;
            fcl[idx] = f2b(fc_w[idx]);
        }
    }
}

// ---- kRed: Wcbf[512][96] bf16 = sum of 8 partials (+b2 on col 80, 0 pads) ---
__global__ __launch_bounds__(1024) void kRed(
    const float* __restrict__ Wcf8, const float* __restrict__ b2,
    unsigned short* __restrict__ Wcbf)
{
    const int idx = blockIdx.x * 1024 + threadIdx.x;   // 48 blocks = 512*96
    const int o = idx / KP, c = idx - o * KP;
    float s = 0.f;
    if (c <= CIN) {
        #pragma unroll
        for (int j = 0; j < 8; ++j)
            s += Wcf8[((size_t)j * 512 + o) * KP + c];
        if (c == CIN) s += b2[o];
    }
    Wcbf[idx] = f2b(s);
}

// ---- kM: one block per batch (R13 config, best measured), ALL 512 groups. ---
// 1024 thr = 16 waves x 32 groups. w3 via packed w3q: 4 x b128 loads per nt
// (was 8 x 8B) — halves VMEM instr, 512 B contiguous per quarter-wave.
__global__ __launch_bounds__(1024) void kM(
    const float* __restrict__ x, const unsigned short* __restrict__ Wcbf,
    const unsigned short* __restrict__ w3q, const unsigned short* __restrict__ fcl,
    const float* __restrict__ fc_b, float* __restrict__ out)
{
    __shared__ __align__(16) unsigned short xs[HWP * XST];  // 43264 B
    __shared__ float gl[2048];                              // 8192 B
    const int b = blockIdx.x, t = threadIdx.x;

    // stage x[b]: [k][hw] f32 (float4: 49 quads/row, no row-crossing) -> xs[hw][k]
    {
        const floatx4* __restrict__ xb4 = (const floatx4*)(x + (size_t)b * CIN * NSP);
        for (int i4 = t; i4 < CIN * 49; i4 += 1024) {
            const int k = i4 / 49, hw4 = (i4 - k * 49) * 4;
            const floatx4 v = xb4[i4];
            xs[(hw4 + 0) * XST + k] = f2b(v[0]);
            xs[(hw4 + 1) * XST + k] = f2b(v[1]);
            xs[(hw4 + 2) * XST + k] = f2b(v[2]);
            xs[(hw4 + 3) * XST + k] = f2b(v[3]);
        }
        // k = 80 -> 1.0 (bias channel), 81..103 -> 0, for hw < 196
        for (int idx = t; idx < NSP * 24; idx += 1024) {
            const int hw = idx / 24, k = 80 + (idx - (idx / 24) * 24);
            xs[hw * XST + k] = (k == CIN) ? (unsigned short)0x3F80 : (unsigned short)0;
        }
        // hw pad rows 196..207: all-zero
        for (int idx = t; idx < 12 * XST; idx += 1024) {
            const int hw = NSP + idx / XST, k = idx - (idx / XST) * XST;
            xs[hw * XST + k] = 0;
        }
    }

    const int w = t >> 6, lane = t & 63;
    const int col = lane & 15, quad = lane >> 4;
    const int gb = w * 32;                 // wave's group base (16 waves x 32 = 512)

    // A-frags: 2 m-tiles x 96 k, bf16 (24 VGPRs), from L2-hot Wcbf
    short8 A[2][3];
    #pragma unroll
    for (int mt = 0; mt < 2; ++mt) {
        const unsigned short* __restrict__ ap =
            Wcbf + (size_t)(gb + mt * 16 + col) * KP + quad * 8;
        #pragma unroll
        for (int ks = 0; ks < 3; ++ks) A[mt][ks] = *(const short8*)(ap + ks * 32);
    }

    float p[2][4][4];   // conv3 partials [mt][r][o]
    #pragma unroll
    for (int mt = 0; mt < 2; ++mt)
        #pragma unroll
        for (int r = 0; r < 4; ++r)
            #pragma unroll
            for (int o = 0; o < 4; ++o) p[mt][r][o] = 0.f;

    const unsigned short* __restrict__ xrow = xs + col * XST + quad * 8;
    // lane's packed w3 rows: gq = gb/4 + mt*4 + quad; addr (gq*HWP + hw)*16
    const unsigned short* __restrict__ wq0 =
        w3q + ((size_t)(gb / 4 + quad) * HWP + col) * 16;
    const unsigned short* __restrict__ wq1 =
        w3q + ((size_t)(gb / 4 + 4 + quad) * HWP + col) * 16;

    __syncthreads();   // staging complete

    #pragma unroll 1
    for (int nt = 0; nt < 13; ++nt) {
        // 4 x b128: 16 bf16 per m-tile = w3[g=quad*4+r][o] for r,o in 0..3
        const ushort8v u0a = *(const ushort8v*)(wq0 + nt * 256);
        const ushort8v u0b = *(const ushort8v*)(wq0 + nt * 256 + 8);
        const ushort8v u1a = *(const ushort8v*)(wq1 + nt * 256);
        const ushort8v u1b = *(const ushort8v*)(wq1 + nt * 256 + 8);
        const unsigned short* __restrict__ xp = xrow + nt * 16 * XST;
        const short8 x0 = *(const short8*)(xp);
        const short8 x1 = *(const short8*)(xp + 32);
        const short8 x2 = *(const short8*)(xp + 64);
        floatx4 a0 = {0.f, 0.f, 0.f, 0.f}, a1 = {0.f, 0.f, 0.f, 0.f};
        a0 = __builtin_amdgcn_mfma_f32_16x16x32_bf16(A[0][0], x0, a0, 0, 0, 0);
        a0 = __builtin_amdgcn_mfma_f32_16x16x32_bf16(A[0][1], x1, a0, 0, 0, 0);
        a0 = __builtin_amdgcn_mfma_f32_16x16x32_bf16(A[0][2], x2, a0, 0, 0, 0);
        a1 = __builtin_amdgcn_mfma_f32_16x16x32_bf16(A[1][0], x0, a1, 0, 0, 0);
        a1 = __builtin_amdgcn_mfma_f32_16x16x32_bf16(A[1][1], x1, a1, 0, 0, 0);
        a1 = __builtin_amdgcn_mfma_f32_16x16x32_bf16(A[1][2], x2, a1, 0, 0, 0);
        // conv3 partials; C/D: col(hw)=lane&15, row(g)=quad*4+r  [m89-verified]
        #pragma unroll
        for (int r = 0; r < 4; ++r) {
            const ushort8v u0 = (r < 2) ? u0a : u0b;
            const ushort8v u1 = (r < 2) ? u1a : u1b;
            const int rb = (r & 1) * 4;
            p[0][r][0] = fmaf(a0[r], b2f(u0[rb + 0]), p[0][r][0]);
            p[0][r][1] = fmaf(a0[r], b2f(u0[rb + 1]), p[0][r][1]);
            p[0][r][2] = fmaf(a0[r], b2f(u0[rb + 2]), p[0][r][2]);
            p[0][r][3] = fmaf(a0[r], b2f(u0[rb + 3]), p[0][r][3]);
            p[1][r][0] = fmaf(a1[r], b2f(u1[rb + 0]), p[1][r][0]);
            p[1][r][1] = fmaf(a1[r], b2f(u1[rb + 1]), p[1][r][1]);
            p[1][r][2] = fmaf(a1[r], b2f(u1[rb + 2]), p[1][r][2]);
            p[1][r][3] = fmaf(a1[r], b2f(u1[rb + 3]), p[1][r][3]);
        }
    }

    // reduce over 16 hw-lanes, relu -> gl[2048]
    #pragma unroll
    for (int mt = 0; mt < 2; ++mt)
        #pragma unroll
        for (int r = 0; r < 4; ++r) {
            float q0 = p[mt][r][0], q1 = p[mt][r][1], q2 = p[mt][r][2], q3 = p[mt][r][3];
            #pragma unroll
            for (int s = 8; s >= 1; s >>= 1) {
                q0 += __shfl_down(q0, s, 16);
                q1 += __shfl_down(q1, s, 16);
                q2 += __shfl_down(q2, s, 16);
                q3 += __shfl_down(q3, s, 16);
            }
            if (col == 0) {
                const int glocal = gb + mt * 16 + quad * 4 + r;
                floatx4 ov = {fmaxf(q0, 0.f), fmaxf(q1, 0.f), fmaxf(q2, 0.f), fmaxf(q3, 0.f)};
                *(floatx4*)(gl + glocal * 4) = ov;
            }
        }
    __syncthreads();

    // fc: wave per l-row (16 waves x 5 rows = 80). Lane reads uint at
    // fcl[l][j*128+2*lane] -> 256 B contiguous per instr; width-64 shfl reduce.
    #pragma unroll 1
    for (int rr = 0; rr < 5; ++rr) {
        const int l = w * 5 + rr;
        const unsigned int* __restrict__ fr =
            (const unsigned int*)(fcl + (size_t)l * 2048) + lane;
        const float* __restrict__ gp = gl + lane * 2;
        float s = 0.f;
        #pragma unroll
        for (int j = 0; j < 16; ++j) {
            const unsigned int u = fr[j * 64];
            float lo, hi;
            { unsigned int a = u << 16;          __builtin_memcpy(&lo, &a, 4); }
            { unsigned int a = u & 0xFFFF0000u;  __builtin_memcpy(&hi, &a, 4); }
            s = fmaf(gp[j * 128    ], lo, s);
            s = fmaf(gp[j * 128 + 1], hi, s);
        }
        #pragma unroll
        for (int sft = 32; sft >= 1; sft >>= 1) s += __shfl_down(s, sft, 64);
        if (lane == 0) out[b * CIN + l] = s + fc_b[l];   // single write, no atomics
    }
}

extern "C" void kernel_launch(void* const* d_in, const int* in_sizes, int n_in,
                              void* d_out, int out_size, void* d_ws, size_t ws_size,
                              hipStream_t stream) {
    const float* x    = (const float*)d_in[0];
    const float* w1   = (const float*)d_in[1];
    const float* b1   = (const float*)d_in[2];
    const float* w2   = (const float*)d_in[3];
    const float* b2   = (const float*)d_in[4];
    const float* w3   = (const float*)d_in[5];
    const float* fc_w = (const float*)d_in[6];
    const float* fc_b = (const float*)d_in[7];
    float* out = (float*)d_out;

    const int B = in_sizes[0] / (CIN * NSP);   // 256

    // workspace: Wcf8 | Wcbf | w3q | fcl  (~2.9 MB)
    char* ws = (char*)d_ws;
    float* Wcf8 = (float*)ws;                                   // 8*512*96*4
    size_t off = (size_t)8 * 512 * KP * 4;
    unsigned short* Wcbf = (unsigned short*)(ws + off); off += 512 * KP * 2;
    unsigned short* w3q  = (unsigned short*)(ws + off); off += (size_t)128 * HWP * 16 * 2;
    unsigned short* fcl  = (unsigned short*)(ws + off);         // 80*2048*2

    kPre<<<NBA + NBC + NBD, 384, 0, stream>>>(w1, b1, w2, w3, fc_w, Wcf8, w3q, fcl);
    kRed<<<48, 1024, 0, stream>>>(Wcf8, b2, Wcbf);
    kM<<<B, 1024, 0, stream>>>(x, Wcbf, w3q, fcl, fc_b, out);
}